// Round 1
// baseline (134.941 us; speedup 1.0000x reference)
//
#include <hip/hip_runtime.h>
#include <math.h>

#define N 16384
#define MD 512
#define CTRLDIM 1024
#define OUTF 1542  // 3*512+6

// ws layout (floats):
//   [0    .. 1541]  O   (projection output o)
//   [2048 .. 2055]  SC  scalars: beta, g, s0, s1, s2, gamma, k_norm
//   [2112 .. 2623]  E   (erase vec, 16B-aligned)
//   [2688 .. 3199]  A   (add vec, 16B-aligned)
//   [4096 .. 20479] Z   (beta * cosine sim, per memory row)

__device__ __forceinline__ float softplus_f(float x) {
    return (x > 20.f) ? x : log1pf(expf(x));
}

// o[row] = dot(W[row,:], emb) + b[row]   (one block per row, 256 thr x 4 elem)
__global__ void k_proj(const float* __restrict__ emb, const float* __restrict__ W,
                       const float* __restrict__ b, float* __restrict__ O) {
    int row = blockIdx.x;
    int t = threadIdx.x;
    const float4* w4 = (const float4*)(W + (size_t)row * CTRLDIM);
    const float4* e4 = (const float4*)emb;
    float4 wv = w4[t];
    float4 ev = e4[t];
    float p = wv.x * ev.x + wv.y * ev.y + wv.z * ev.z + wv.w * ev.w;
    #pragma unroll
    for (int off = 32; off; off >>= 1) p += __shfl_down(p, off, 64);
    __shared__ float s[4];
    int lane = t & 63, wid = t >> 6;
    if (lane == 0) s[wid] = p;
    __syncthreads();
    if (t == 0) O[row] = s[0] + s[1] + s[2] + s[3] + b[row];
}

// scalars (k_norm, beta, g, softmax s, gamma) + aligned copies of e, a
__global__ void k_scal(const float* __restrict__ O, float* __restrict__ SC,
                       float* __restrict__ E, float* __restrict__ A) {
    int t = threadIdx.x;  // 512
    float kv = O[t];
    float sq = kv * kv;
    #pragma unroll
    for (int off = 32; off; off >>= 1) sq += __shfl_down(sq, off, 64);
    __shared__ float s[8];
    int lane = t & 63, wid = t >> 6;
    if (lane == 0) s[wid] = sq;
    E[t] = O[MD + 6 + t];
    A[t] = O[2 * MD + 6 + t];
    __syncthreads();
    if (t == 0) {
        float ksq = 0.f;
        #pragma unroll
        for (int i = 0; i < 8; i++) ksq += s[i];
        float knorm = sqrtf(ksq);
        float beta = softplus_f(O[MD]);
        float g = 1.f / (1.f + expf(-O[MD + 1]));
        float s0 = O[MD + 2], s1 = O[MD + 3], s2 = O[MD + 4];
        float m = fmaxf(s0, fmaxf(s1, s2));
        float e0 = expf(s0 - m), e1 = expf(s1 - m), e2 = expf(s2 - m);
        float se = e0 + e1 + e2;
        float gamma = 1.f + softplus_f(O[MD + 5]);
        SC[0] = beta; SC[1] = g; SC[2] = e0 / se; SC[3] = e1 / se; SC[4] = e2 / se;
        SC[5] = gamma; SC[6] = knorm;
    }
}

// Z[row] = beta * dot(k, mem[row]) / (|k| * |mem[row]| + EPS)  (wave per row)
__global__ void k_sim(const float* __restrict__ mem, const float* __restrict__ O,
                      const float* __restrict__ SC, float* __restrict__ Z) {
    int wid = threadIdx.x >> 6;
    int lane = threadIdx.x & 63;
    int row = blockIdx.x * 4 + wid;
    const float4* m4 = (const float4*)(mem + (size_t)row * MD);
    const float4* k4 = (const float4*)O;
    float dot = 0.f, nsq = 0.f;
    #pragma unroll
    for (int c = 0; c < 2; c++) {
        int j = lane + c * 64;
        float4 m = m4[j];
        float4 k = k4[j];
        dot += m.x * k.x + m.y * k.y + m.z * k.z + m.w * k.w;
        nsq += m.x * m.x + m.y * m.y + m.z * m.z + m.w * m.w;
    }
    #pragma unroll
    for (int off = 32; off; off >>= 1) {
        dot += __shfl_down(dot, off, 64);
        nsq += __shfl_down(nsq, off, 64);
    }
    if (lane == 0) {
        float beta = SC[0], knorm = SC[6];
        Z[row] = beta * dot / (knorm * sqrtf(nsq) + 1e-16f);
    }
}

// single block: softmax(Z) -> interpolate -> circular shift -> sharpen -> normalize
__global__ void __launch_bounds__(1024) k_soft(const float* __restrict__ Z,
                                               const float* __restrict__ wprev,
                                               const float* __restrict__ SC,
                                               float* __restrict__ wout) {
    __shared__ float red[1024];
    __shared__ float sfirst[1024];
    __shared__ float slast[1024];
    int t = threadIdx.x;
    const int C = 16;
    int base = t * C;
    float z[C];
    float mx = -1e30f;
    #pragma unroll
    for (int j = 0; j < C; j++) { z[j] = Z[base + j]; mx = fmaxf(mx, z[j]); }
    // block max
    red[t] = mx; __syncthreads();
    #pragma unroll
    for (int off = 512; off; off >>= 1) {
        if (t < off) red[t] = fmaxf(red[t], red[t + off]);
        __syncthreads();
    }
    mx = red[0]; __syncthreads();
    // exp + block sum
    float sum = 0.f;
    #pragma unroll
    for (int j = 0; j < C; j++) { z[j] = expf(z[j] - mx); sum += z[j]; }
    red[t] = sum; __syncthreads();
    #pragma unroll
    for (int off = 512; off; off >>= 1) {
        if (t < off) red[t] += red[t + off];
        __syncthreads();
    }
    float inv = 1.f / red[0]; __syncthreads();
    float g = SC[1], s0 = SC[2], s1 = SC[3], s2 = SC[4], gamma = SC[5];
    // wc -> wg (in registers)
    #pragma unroll
    for (int j = 0; j < C; j++) {
        float wc = z[j] * inv;
        z[j] = g * wc + (1.f - g) * wprev[base + j];
    }
    sfirst[t] = z[0];
    slast[t] = z[C - 1];
    __syncthreads();
    // ws_i = s0*wg[i-1] + s1*wg[i] + s2*wg[i+1] (circular); wp = (ws+EPS)^gamma
    float wp[C];
    float sum2 = 0.f;
    #pragma unroll
    for (int j = 0; j < C; j++) {
        float left  = (j == 0)     ? slast[(t + 1023) & 1023] : z[j - 1];
        float right = (j == C - 1) ? sfirst[(t + 1) & 1023]   : z[j + 1];
        float wsv = s0 * left + s1 * z[j] + s2 * right;
        float p = powf(wsv + 1e-16f, gamma);
        wp[j] = p;
        sum2 += p;
    }
    red[t] = sum2; __syncthreads();
    #pragma unroll
    for (int off = 512; off; off >>= 1) {
        if (t < off) red[t] += red[t + off];
        __syncthreads();
    }
    float invt = 1.f / red[0];
    #pragma unroll
    for (int j = 0; j < C; j++) wout[base + j] = wp[j] * invt;
}

// new_memory = memory * (1 - w_i * e_j) + w_i * a_j
__global__ void k_upd(const float* __restrict__ mem, const float* __restrict__ w,
                      const float* __restrict__ E, const float* __restrict__ A,
                      float* __restrict__ outMem) {
    int idx = blockIdx.x * blockDim.x + threadIdx.x;  // 0 .. N*128-1 (float4 units)
    int i = idx >> 7;
    int c = idx & 127;
    float wi = w[i];
    float4 m = ((const float4*)mem)[idx];
    float4 e = ((const float4*)E)[c];
    float4 a = ((const float4*)A)[c];
    float4 o;
    o.x = m.x * (1.f - wi * e.x) + wi * a.x;
    o.y = m.y * (1.f - wi * e.y) + wi * a.y;
    o.z = m.z * (1.f - wi * e.z) + wi * a.z;
    o.w = m.w * (1.f - wi * e.w) + wi * a.w;
    ((float4*)outMem)[idx] = o;
}

extern "C" void kernel_launch(void* const* d_in, const int* in_sizes, int n_in,
                              void* d_out, int out_size, void* d_ws, size_t ws_size,
                              hipStream_t stream) {
    const float* emb   = (const float*)d_in[0];
    const float* wprev = (const float*)d_in[1];
    const float* mem   = (const float*)d_in[2];
    const float* W     = (const float*)d_in[3];
    const float* b     = (const float*)d_in[4];
    float* out = (float*)d_out;
    float* wsf = (float*)d_ws;
    float* O  = wsf;
    float* SC = wsf + 2048;
    float* E  = wsf + 2112;
    float* A  = wsf + 2688;
    float* Z  = wsf + 4096;

    k_proj<<<OUTF, 256, 0, stream>>>(emb, W, b, O);
    k_scal<<<1, 512, 0, stream>>>(O, SC, E, A);
    k_sim<<<N / 4, 256, 0, stream>>>(mem, O, SC, Z);
    k_soft<<<1, 1024, 0, stream>>>(Z, wprev, SC, out);
    k_upd<<<(N * (MD / 4)) / 256, 256, 0, stream>>>(mem, out, E, A, out + N);
}